// Round 13
// baseline (733.783 us; speedup 1.0000x reference)
//
#include <hip/hip_runtime.h>

#define KS 3
#define NN 65536
#define EE 524288
#define BB 64

typedef unsigned short u16;
typedef unsigned int u32;

typedef __attribute__((ext_vector_type(8))) short bf16x8;
typedef __attribute__((ext_vector_type(4))) float f32x4;

__device__ __forceinline__ float bf2f(u16 u) {
  union { u32 i; float f; } v; v.i = ((u32)u) << 16; return v.f;
}
__device__ __forceinline__ u16 f2bf(float f) {
  union { float f; u32 i; } v; v.f = f;
  u32 x = v.i;
  x += 0x7fffu + ((x >> 16) & 1u);   // RNE
  return (u16)(x >> 16);
}

// ---------------- ws byte offsets (peak 85.08 MB <= proven 99.39 MB) ----------------
static const size_t O_CR   = 0;                    // E x 5 u32
static const size_t O_ROWS = 10485760;             // (N+1) i32, padded 262,400
static const size_t O_CURS = 10748160;             // N i32
static const size_t O_BSUM = 11010304;             // 256 i32 pad 1024
static const size_t O_BMAT = 11011328;             // packed B mats 368,640
static const size_t O_XB   = 11379968;             // N*16 bf16 + 64 slack
static const size_t O_H1   = 13477184;             // N*32 bf16
static const size_t O_H2   = 17671488;             // N*64 bf16
static const size_t O_H3   = 26060096;             // N*64 bf16
static const size_t O_D0   = 34448704;             // N*64 bf16
static const size_t O_D1   = 42837312;             // N*32 bf16
static const size_t O_HBUF = 47031616;             // 64*128 f32
static const size_t O_DEG  = 47064384;             // N i32
static const size_t O_AGG2 = 47326528;             // N*576 bf16 = 37,748,736 (enc2 agg for dec0)

// ---------------- x f32 -> bf16 ----------------
__global__ void cvt_x(const float* __restrict__ x, u16* __restrict__ xb) {
  int i = blockIdx.x * 256 + threadIdx.x;
  xb[i] = f2bf(x[i]);
}

// ---------------- prep: degree histogram ----------------
__global__ void hist_kernel(const int* __restrict__ ei, int* __restrict__ deg) {
  int e = blockIdx.x * 256 + threadIdx.x;
  int d = ei[EE + e]; d = min(max(d, 0), NN - 1);
  atomicAdd(&deg[d], 1);
}

// ---------------- scans ----------------
__global__ void scan1(const int* __restrict__ deg, int* __restrict__ rows,
                      int* __restrict__ bsum) {
  __shared__ int s[256];
  int t = threadIdx.x, b = blockIdx.x, i = b * 256 + t;
  int v = deg[i];
  s[t] = v; __syncthreads();
  for (int off = 1; off < 256; off <<= 1) {
    int x = (t >= off) ? s[t - off] : 0; __syncthreads();
    s[t] += x; __syncthreads();
  }
  rows[i] = s[t] - v;
  if (t == 255) bsum[b] = s[255];
}
__global__ void scan2(int* __restrict__ bsum) {
  __shared__ int s[256];
  int t = threadIdx.x;
  int v = bsum[t];
  s[t] = v; __syncthreads();
  for (int off = 1; off < 256; off <<= 1) {
    int x = (t >= off) ? s[t - off] : 0; __syncthreads();
    s[t] += x; __syncthreads();
  }
  bsum[t] = s[t] - v;
}
__global__ void scan3(int* __restrict__ rows, const int* __restrict__ bsum,
                      int* __restrict__ cursor) {
  int t = threadIdx.x, b = blockIdx.x, i = b * 256 + t;
  int v = rows[i] + bsum[b];
  rows[i] = v;
  cursor[i] = v;
  if (i == NN - 1) rows[NN] = EE;
}

// ---------------- fill CSR rows ----------------
__global__ void fill_kernel(const int* __restrict__ ei, const float* __restrict__ pos,
                            int* __restrict__ cursor, u32* __restrict__ cr) {
  int e = blockIdx.x * 256 + threadIdx.x;
  int src = ei[e];      src = min(max(src, 0), NN - 1);
  int dst = ei[EE + e]; dst = min(max(dst, 0), NN - 1);
  float2 p = ((const float2*)pos)[e];
  float fl0 = floorf(p.x), fl1 = floorf(p.y);
  float f0 = p.x - fl0, f1 = p.y - fl1;
  int b0 = (int)fl0, b1 = (int)fl1;
  float w0[3] = { 0.5f*(1.f-f0)*(1.f-f0), -f0*f0+f0+0.5f, 0.5f*f0*f0 };
  float w1[3] = { 0.5f*(1.f-f1)*(1.f-f1), -f1*f1+f1+0.5f, 0.5f*f1*f1 };
  int i0[3], i1[3];
#pragma unroll
  for (int s = 0; s < 3; ++s) {
    i0[s] = min(max(b0 + s, 0), KS - 1);
    i1[s] = min(max(b1 + s, 0), KS - 1);
  }
  float c[9] = {0,0,0,0,0,0,0,0,0};
#pragma unroll
  for (int s0 = 0; s0 < 3; ++s0)
#pragma unroll
    for (int s1 = 0; s1 < 3; ++s1)
      c[i0[s0] + KS * i1[s1]] += w0[s0] * w1[s1];
  u16 h[9];
#pragma unroll
  for (int k = 0; k < 9; ++k) h[k] = f2bf(c[k]);
  int slot = atomicAdd(&cursor[dst], 1);
  slot = min(max(slot, 0), EE - 1);
  size_t b = (size_t)slot * 5;
  cr[b + 0] = (u32)(u16)src | ((u32)h[0] << 16);
  cr[b + 1] = (u32)h[1] | ((u32)h[2] << 16);
  cr[b + 2] = (u32)h[3] | ((u32)h[4] << 16);
  cr[b + 3] = (u32)h[5] | ((u32)h[6] << 16);
  cr[b + 4] = (u32)h[7] | ((u32)h[8] << 16);
}

// ---------------- build packed B matrices ----------------
// type 0: spline chunk K=288; type 1: root; type 2: chunked-K 576 (agg_h2 -> W_d0[64:128]).
struct BDesc { const float* W; int dstOff, i0, INW, OUT, K, type; };
struct BDescs { BDesc d[17]; };

__global__ void build_b(BDescs ds, u16* __restrict__ bmat) {
  BDesc d = ds.d[blockIdx.y];
  int idx = blockIdx.x * 256 + threadIdx.x;
  int elems = d.K * d.OUT;
  if (idx >= elems) return;
  int o = idx / d.K, r = idx - o * d.K;
  float v;
  if (d.type == 1) {
    v = (r < d.INW) ? d.W[(size_t)(d.i0 + r) * d.OUT + o] : 0.f;
  } else if (d.type == 2) {
    int cc = r / 288, rem = r - cc * 288;
    int kk = rem >> 5, ii = rem & 31;
    int i = d.i0 + cc * 32 + ii;
    v = d.W[((size_t)kk * d.INW + i) * d.OUT + o];
  } else {
    int kk = r >> 5, ii = r & 31;
    int i = d.i0 + ii;
    v = (i < d.INW) ? d.W[((size_t)kk * d.INW + i) * d.OUT + o] : 0.f;
  }
  bmat[(size_t)d.dstOff + (size_t)o * d.K + r] = f2bf(v);
}

// ---------------- fused layer, v5: single-walk + optional agg store + streamed reuse ----------------
// block = 256 thr = 4 waves sharing ONE 8-node tile; 8 blocks/CU = 32 waves/CU.
struct PD { const u16* src; const u16* src2; int IN, IN2, mode, bOffA, ncA, bOffB, ncB; };
struct RD { const u16* src; int astride, ksteps, bOff; };
struct FArgs { PD ch; RD rt[3]; int nrt; const float* bias; u16* dst; u16* aggOut; };

#define NSTRIDE 1192   // u16 per node row: 4 chunks x 296 + 8 pad

#define DECODE9U(Q0)                                              \
    u32 q1 = __builtin_amdgcn_readfirstlane(p[1]);                \
    u32 q2 = __builtin_amdgcn_readfirstlane(p[2]);                \
    u32 q3 = __builtin_amdgcn_readfirstlane(p[3]);                \
    u32 q4 = __builtin_amdgcn_readfirstlane(p[4]);                \
    float c0 = bf2f((u16)((Q0) >> 16));                           \
    float c1 = bf2f((u16)(q1 & 0xffffu)), c2 = bf2f((u16)(q1 >> 16)); \
    float c3 = bf2f((u16)(q2 & 0xffffu)), c4 = bf2f((u16)(q2 >> 16)); \
    float c5 = bf2f((u16)(q3 & 0xffffu)), c6 = bf2f((u16)(q3 >> 16)); \
    float c7 = bf2f((u16)(q4 & 0xffffu)), c8 = bf2f((u16)(q4 >> 16));

#define DECODE9V(Q0)                                              \
    u32 q1 = p[1], q2 = p[2], q3 = p[3], q4 = p[4];               \
    float c0 = bf2f((u16)((Q0) >> 16));                           \
    float c1 = bf2f((u16)(q1 & 0xffffu)), c2 = bf2f((u16)(q1 >> 16)); \
    float c3 = bf2f((u16)(q2 & 0xffffu)), c4 = bf2f((u16)(q2 >> 16)); \
    float c5 = bf2f((u16)(q3 & 0xffffu)), c6 = bf2f((u16)(q3 >> 16)); \
    float c7 = bf2f((u16)(q4 & 0xffffu)), c8 = bf2f((u16)(q4 >> 16));

#define ACC9(DST, XV) do {                                        \
    DST[0] = fmaf(c0, (XV), DST[0]); DST[1] = fmaf(c1, (XV), DST[1]); \
    DST[2] = fmaf(c2, (XV), DST[2]); DST[3] = fmaf(c3, (XV), DST[3]); \
    DST[4] = fmaf(c4, (XV), DST[4]); DST[5] = fmaf(c5, (XV), DST[5]); \
    DST[6] = fmaf(c6, (XV), DST[6]); DST[7] = fmaf(c7, (XV), DST[7]); \
    DST[8] = fmaf(c8, (XV), DST[8]); } while (0)

template <int OUT>
__global__ __launch_bounds__(256, 8) void fused_layer(FArgs fa, const u32* __restrict__ cr,
                                                      const int* __restrict__ rows,
                                                      const u16* __restrict__ bmat) {
  __shared__ u16 aggl[8 * NSTRIDE];
  constexpr int NT = OUT / 16;
  const int tid = threadIdx.x;
  const int wave = tid >> 6, lane = tid & 63;
  const int quad = lane >> 4, l16 = lane & 15;
  const int l = lane & 31, half = lane >> 5;
  const int nb = blockIdx.x * 8;

  const PD d = fa.ch;
  if (d.mode == 0) {
    // ---- full-wave: lane = feature; optional dual-line; 4-edge groups ----
    const bool has2 = d.src2 != nullptr;
    const bool v2 = has2 && (lane < d.IN2);
    const u16* sp  = d.src + lane;
    const u16* sp2 = has2 ? d.src2 + (v2 ? lane : 0) : nullptr;
    const int st2 = d.IN2;
    const int cslot  = half * 296 + l;           // chunks 0-1
    const int cslotB = 2 * 296 + half * 296 + l; // chunks 2-3
    for (int nn = 0; nn < 2; ++nn) {
      const int node = nb + wave * 2 + nn;
      const int rs = rows[node], re = rows[node + 1];
      float a[9] = {0,0,0,0,0,0,0,0,0};
      float b9[9] = {0,0,0,0,0,0,0,0,0};
      int r = rs;
      for (; r + 3 < re; r += 4) {
        u32 w0[4]; float xv[4], yv[4];
#pragma unroll
        for (int g = 0; g < 4; ++g) w0[g] = cr[(size_t)(r + g) * 5];
#pragma unroll
        for (int g = 0; g < 4; ++g)
          xv[g] = bf2f(sp[(size_t)(w0[g] & 0xffffu) * 64]);
        if (has2) {
#pragma unroll
          for (int g = 0; g < 4; ++g)
            yv[g] = v2 ? bf2f(sp2[(size_t)(w0[g] & 0xffffu) * st2]) : 0.f;
        }
#pragma unroll
        for (int g = 0; g < 4; ++g) {
          const u32* p = cr + (size_t)(r + g) * 5;
          u32 q0 = __builtin_amdgcn_readfirstlane(w0[g]);
          DECODE9U(q0);
          ACC9(a, xv[g]);
          if (has2) ACC9(b9, yv[g]);
        }
      }
      for (; r < re; ++r) {
        const u32* p = cr + (size_t)r * 5;
        u32 w0 = p[0];
        float xv = bf2f(sp[(size_t)(w0 & 0xffffu) * 64]);
        float yv = 0.f;
        if (has2) yv = v2 ? bf2f(sp2[(size_t)(w0 & 0xffffu) * st2]) : 0.f;
        u32 q0 = __builtin_amdgcn_readfirstlane(w0);
        DECODE9U(q0);
        ACC9(a, xv);
        if (has2) ACC9(b9, yv);
      }
      const float inv = 1.f / fmaxf((float)(re - rs), 1.f);
      const int row = wave * 2 + nn;
#pragma unroll
      for (int k = 0; k < 9; ++k)
        aggl[row * NSTRIDE + cslot + k * 32] = f2bf(a[k] * inv);
      if (has2) {
#pragma unroll
        for (int k = 0; k < 9; ++k)
          aggl[row * NSTRIDE + cslotB + k * 32] = f2bf(b9[k] * inv);
      }
    }
  } else {
    // ---- half-wave: lane%32 = feature, 2 edges in flight (per-lane decode) ----
    const int i = l;
    const bool valid = i < d.IN;
    const u16* sp = d.src + i;
    const int IN = d.IN;
    for (int nn = 0; nn < 2; ++nn) {
      const int node = nb + wave * 2 + nn;
      const int rs = rows[node], re = rows[node + 1];
      float a[9] = {0,0,0,0,0,0,0,0,0};
      int r = rs + half;
      for (; r + 2 < re; r += 4) {
        u32 w0[2]; float xv[2];
#pragma unroll
        for (int g = 0; g < 2; ++g) w0[g] = cr[(size_t)(r + 2 * g) * 5];
#pragma unroll
        for (int g = 0; g < 2; ++g)
          xv[g] = valid ? bf2f(sp[(size_t)(w0[g] & 0xffffu) * IN]) : 0.f;
#pragma unroll
        for (int g = 0; g < 2; ++g) {
          const u32* p = cr + (size_t)(r + 2 * g) * 5;
          u32 q0 = w0[g];
          DECODE9V(q0);
          ACC9(a, xv[g]);
        }
      }
      for (; r < re; r += 2) {
        const u32* p = cr + (size_t)r * 5;
        u32 q0 = p[0];
        float xv = valid ? bf2f(sp[(size_t)(q0 & 0xffffu) * IN]) : 0.f;
        DECODE9V(q0);
        ACC9(a, xv);
      }
#pragma unroll
      for (int k = 0; k < 9; ++k) a[k] += __shfl_xor(a[k], 32);
      const float inv = 1.f / fmaxf((float)(re - rs), 1.f);
      if (half == 0) {
#pragma unroll
        for (int k = 0; k < 9; ++k)
          aggl[(wave * 2 + nn) * NSTRIDE + k * 32 + l] = f2bf(a[k] * inv);
      }
    }
  }
  __syncthreads();

  // ---- optional agg dump: LDS tile -> [node][576] u16, coalesced full lines ----
  if (fa.aggOut) {
    u32* dstw = (u32*)fa.aggOut;
#pragma unroll
    for (int it = 0; it < 9; ++it) {
      int idx = it * 256 + tid;            // 0..2303 ; 288 u32 per node
      int node = idx / 288;
      int e = idx - node * 288;
      int w = 2 * e;                        // u16 index in [0,576)
      int chunk = (w >= 288) ? 1 : 0;
      int wc = w - chunk * 288;
      int k = wc >> 5, ll = wc & 31;
      u32 v = *(const u32*)&aggl[node * NSTRIDE + chunk * 296 + k * 32 + ll];
      dstw[(size_t)(nb + node) * 288 + e] = v;
    }
  }

  if (wave < NT) {
    f32x4 C = (f32x4){0.f, 0.f, 0.f, 0.f};
    for (int cc = 0; cc < d.ncA; ++cc) {
      const u16* Bp = bmat + d.bOffA + cc * 288 * OUT;
      for (int ks = 0; ks < 9; ++ks) {
        bf16x8 av = *(const bf16x8*)&aggl[l16 * NSTRIDE + cc * 296 + ks * 32 + quad * 8];
        bf16x8 bv = *(const bf16x8*)(Bp + ((size_t)(wave * 16 + l16) * 9 + ks) * 32 + quad * 8);
        C = __builtin_amdgcn_mfma_f32_16x16x32_bf16(av, bv, C, 0, 0, 0);
      }
    }
    for (int cc = 0; cc < d.ncB; ++cc) {
      const u16* Bp = bmat + d.bOffB + cc * 288 * OUT;
      for (int ks = 0; ks < 9; ++ks) {
        bf16x8 av = *(const bf16x8*)&aggl[l16 * NSTRIDE + (2 + cc) * 296 + ks * 32 + quad * 8];
        bf16x8 bv = *(const bf16x8*)(Bp + ((size_t)(wave * 16 + l16) * 9 + ks) * 32 + quad * 8);
        C = __builtin_amdgcn_mfma_f32_16x16x32_bf16(av, bv, C, 0, 0, 0);
      }
    }
    // streamed passes: agg reuse + root linears (A direct from global; overread harmless)
    for (int rx = 0; rx < fa.nrt; ++rx) {
      const RD rd = fa.rt[rx];
      for (int ks = 0; ks < rd.ksteps; ++ks) {
        bf16x8 av = *(const bf16x8*)(rd.src + (size_t)(nb + l16) * rd.astride + ks * 32 + quad * 8);
        bf16x8 bv = *(const bf16x8*)(bmat + rd.bOff
                     + ((size_t)(wave * 16 + l16) * rd.ksteps + ks) * 32 + quad * 8);
        C = __builtin_amdgcn_mfma_f32_16x16x32_bf16(av, bv, C, 0, 0, 0);
      }
    }
    if (quad < 2) {
#pragma unroll
      for (int r = 0; r < 4; ++r) {
        int node = nb + quad * 4 + r;
        int o = wave * 16 + l16;
        float v = C[r] + fa.bias[o];
        v = fminf(fmaxf(v, 0.f), 6.f);
        fa.dst[(size_t)node * OUT + o] = f2bf(v);
      }
    }
  }
}

// ---------------- final MLP ----------------
__global__ __launch_bounds__(256) void mlp1(const u16* __restrict__ d1,
                                            const float* __restrict__ w1,
                                            float* __restrict__ hbuf) {
  __shared__ __align__(16) u16 bt[128 * 136];
  const int tid = threadIdx.x;
  const int c0 = blockIdx.x * 128;
  for (int idx = tid; idx < 16384; idx += 256) {
    int k = idx >> 7, col = idx & 127;
    bt[col * 136 + k] = f2bf(w1[(size_t)(c0 + k) * 128 + col]);
  }
  __syncthreads();
  const int wave = tid >> 6, lane = tid & 63;
  const int quad = lane >> 4, l16 = lane & 15;
  f32x4 C[8];
#pragma unroll
  for (int nt = 0; nt < 8; ++nt) C[nt] = (f32x4){0.f, 0.f, 0.f, 0.f};
  for (int ks = 0; ks < 4; ++ks) {
    bf16x8 av = *(const bf16x8*)(d1 + (size_t)(wave * 16 + l16) * 32768 + c0 + ks * 32 + quad * 8);
#pragma unroll
    for (int nt = 0; nt < 8; ++nt) {
      bf16x8 bv = *(const bf16x8*)&bt[(nt * 16 + l16) * 136 + ks * 32 + quad * 8];
      C[nt] = __builtin_amdgcn_mfma_f32_16x16x32_bf16(av, bv, C[nt], 0, 0, 0);
    }
  }
#pragma unroll
  for (int nt = 0; nt < 8; ++nt)
#pragma unroll
    for (int r = 0; r < 4; ++r) {
      int g = wave * 16 + quad * 4 + r;
      int o = nt * 16 + l16;
      atomicAdd(&hbuf[g * 128 + o], C[nt][r]);
    }
}

__global__ void mlp2(const float* __restrict__ hbuf, const float* __restrict__ b1,
                     const float* __restrict__ w2, const float* __restrict__ b2,
                     float* __restrict__ out) {
  const int t = threadIdx.x;
  if (t >= BB * 3) return;
  const int g = t / 3, c = t % 3;
  float acc = b2[c];
  for (int j = 0; j < 128; ++j) {
    float h = fmaxf(hbuf[g * 128 + j] + b1[j], 0.f);
    acc = fmaf(h, w2[j * 3 + c], acc);
  }
  out[g * 3 + c] = acc;
}

// ---------------- launch ----------------
extern "C" void kernel_launch(void* const* d_in, const int* in_sizes, int n_in,
                              void* d_out, int out_size, void* d_ws, size_t ws_size,
                              hipStream_t stream) {
  const float* x   = (const float*)d_in[0];
  const int*   ei  = (const int*)d_in[1];
  const float* pos = (const float*)d_in[2];

  char* base = (char*)d_ws;
  u32*   cr     = (u32*)(base + O_CR);
  int*   rows   = (int*)(base + O_ROWS);
  int*   cursor = (int*)(base + O_CURS);
  int*   bsum   = (int*)(base + O_BSUM);
  u16*   bmat   = (u16*)(base + O_BMAT);
  u16*   xb     = (u16*)(base + O_XB);
  u16*   h1     = (u16*)(base + O_H1);
  u16*   h2     = (u16*)(base + O_H2);
  u16*   h3     = (u16*)(base + O_H3);
  u16*   d0     = (u16*)(base + O_D0);
  u16*   d1     = (u16*)(base + O_D1);
  float* hbuf   = (float*)(base + O_HBUF);
  int*   deg    = (int*)(base + O_DEG);
  u16*   agg2   = (u16*)(base + O_AGG2);

  hipMemsetAsync(base + O_HBUF, 0, 32768 + 262144, stream);   // hbuf + deg

  cvt_x<<<NN * 16 / 256, 256, 0, stream>>>(x, xb);
  hist_kernel<<<EE / 256, 256, 0, stream>>>(ei, deg);
  scan1<<<256, 256, 0, stream>>>(deg, rows, bsum);
  scan2<<<1, 256, 0, stream>>>(bsum);
  scan3<<<256, 256, 0, stream>>>(rows, bsum, cursor);
  fill_kernel<<<EE / 256, 256, 0, stream>>>(ei, pos, cursor, cr);

  const float* W_e0 = (const float*)d_in[4];
  const float* R_e0 = (const float*)d_in[5];
  const float* B_e0 = (const float*)d_in[6];
  const float* W_e1 = (const float*)d_in[7];
  const float* R_e1 = (const float*)d_in[8];
  const float* B_e1 = (const float*)d_in[9];
  const float* W_e2 = (const float*)d_in[10];
  const float* R_e2 = (const float*)d_in[11];
  const float* B_e2 = (const float*)d_in[12];
  const float* W_d0 = (const float*)d_in[13];
  const float* R_d0 = (const float*)d_in[14];
  const float* B_d0 = (const float*)d_in[15];
  const float* W_d1 = (const float*)d_in[16];
  const float* R_d1 = (const float*)d_in[17];
  const float* B_d1 = (const float*)d_in[18];

  BDescs ds;
  ds.d[0]  = { W_e0, 0,      0,  16,  32, 288, 0 };
  ds.d[1]  = { W_e1, 9216,   0,  32,  64, 288, 0 };
  ds.d[2]  = { W_e2, 27648,  0,  64,  64, 288, 0 };
  ds.d[3]  = { W_e2, 46080,  32, 64,  64, 288, 0 };
  ds.d[4]  = { W_d0, 64512,  0,  128, 64, 288, 0 };
  ds.d[5]  = { W_d0, 82944,  32, 128, 64, 288, 0 };
  ds.d[6]  = { W_d0, 101376, 64, 128, 64, 576, 2 };   // K=576 chunked mat (agg_h2 pass)
  ds.d[7]  = { W_d1, 138240, 0,  96,  32, 288, 0 };
  ds.d[8]  = { W_d1, 147456, 32, 96,  32, 288, 0 };
  ds.d[9]  = { W_d1, 156672, 64, 96,  32, 288, 0 };
  ds.d[10] = { R_e0, 165888, 0,  16, 32, 32, 1 };
  ds.d[11] = { R_e1, 166912, 0,  32, 64, 32, 1 };
  ds.d[12] = { R_e2, 168960, 0,  64, 64, 64, 1 };
  ds.d[13] = { R_d0, 173056, 0,  64, 64, 64, 1 };
  ds.d[14] = { R_d0, 177152, 64, 64, 64, 64, 1 };
  ds.d[15] = { R_d1, 181248, 0,  64, 32, 64, 1 };
  ds.d[16] = { R_d1, 183296, 64, 32, 32, 32, 1 };
  build_b<<<dim3(144, 17), 256, 0, stream>>>(ds, bmat);

  const int FG = NN / 8;   // 8192 blocks x 4 waves, 8 nodes/block

  FArgs fe0 = { {xb, nullptr, 16, 0, 1, 0, 1, 0, 0},
                { {xb, 16, 1, 165888}, {}, {} }, 1, B_e0, h1, nullptr };
  fused_layer<32><<<FG, 256, 0, stream>>>(fe0, cr, rows, bmat);

  FArgs fe1 = { {h1, nullptr, 32, 0, 1, 9216, 1, 0, 0},
                { {h1, 32, 1, 166912}, {}, {} }, 1, B_e1, h2, nullptr };
  fused_layer<64><<<FG, 256, 0, stream>>>(fe1, cr, rows, bmat);

  // enc2: gather h2 (full-wave, 2 chunks) + root; ALSO dump agg_h2 for dec0 reuse
  FArgs fe2 = { {h2, nullptr, 64, 0, 0, 27648, 2, 0, 0},
                { {h2, 64, 2, 168960}, {}, {} }, 1, B_e2, h3, agg2 };
  fused_layer<64><<<FG, 256, 0, stream>>>(fe2, cr, rows, bmat);

  // dec0: single h3 gather + streamed agg_h2 (K=576) + roots h3, h2
  FArgs fd0 = { {h3, nullptr, 64, 0, 0, 64512, 2, 0, 0},
                { {agg2, 576, 18, 101376}, {h3, 64, 2, 173056}, {h2, 64, 2, 177152} },
                3, B_d0, d0, nullptr };
  fused_layer<64><<<FG, 256, 0, stream>>>(fd0, cr, rows, bmat);

  // dec1: single walk gathers d0 + h1 (dual-line); roots d0, h1
  FArgs fd1 = { {d0, h1, 64, 32, 0, 138240, 2, 156672, 1},
                { {d0, 64, 2, 181248}, {h1, 32, 1, 183296}, {} }, 2, B_d1, d1, nullptr };
  fused_layer<32><<<FG, 256, 0, stream>>>(fd1, cr, rows, bmat);

  mlp1<<<256, 256, 0, stream>>>(d1, (const float*)d_in[19], hbuf);
  mlp2<<<1, 256, 0, stream>>>(hbuf, (const float*)d_in[20], (const float*)d_in[21],
                              (const float*)d_in[22], (float*)d_out);
}

// Round 14
// 614.534 us; speedup vs baseline: 1.1940x; 1.1940x over previous
//
#include <hip/hip_runtime.h>

#define KS 3
#define NN 65536
#define EE 524288
#define BB 64

typedef unsigned short u16;
typedef unsigned int u32;

typedef __attribute__((ext_vector_type(8))) short bf16x8;
typedef __attribute__((ext_vector_type(4))) float f32x4;

__device__ __forceinline__ float bf2f(u16 u) {
  union { u32 i; float f; } v; v.i = ((u32)u) << 16; return v.f;
}
__device__ __forceinline__ u16 f2bf(float f) {
  union { float f; u32 i; } v; v.f = f;
  u32 x = v.i;
  x += 0x7fffu + ((x >> 16) & 1u);   // RNE
  return (u16)(x >> 16);
}

// ---------------- ws byte offsets (peak 72.5 MB) ----------------
static const size_t O_CR   = 0;                    // E x 5 u32
static const size_t O_ROWS = 10485760;             // (N+1) i32, padded 262,400
static const size_t O_CURS = 10748160;             // N i32
static const size_t O_BSUM = 11010304;             // 256 i32 pad 1024
static const size_t O_BMAT = 11011328;             // packed B mats 368,640
static const size_t O_XB   = 11379968;             // N*16 bf16 + 64 slack
static const size_t O_H1   = 13477184;             // N*32 bf16
static const size_t O_H2   = 17671488;             // N*64 bf16
static const size_t O_H3   = 26060096;             // N*64 bf16
static const size_t O_D0   = 34448704;             // N*64 bf16
static const size_t O_D1   = 42837312;             // N*32 bf16
static const size_t O_HBUF = 47031616;             // 64*128 f32
static const size_t O_DEG  = 47064384;             // N i32
static const size_t O_PD0  = 47326528;             // N*64 f32 = 16,777,216 (enc2 -> dec0 partial)
static const size_t O_PD1  = 64103744;             // N*32 f32 =  8,388,608 (enc1 -> dec1 partial)
// end = 72,492,352

// ---------------- x f32 -> bf16 ----------------
__global__ void cvt_x(const float* __restrict__ x, u16* __restrict__ xb) {
  int i = blockIdx.x * 256 + threadIdx.x;
  xb[i] = f2bf(x[i]);
}

// ---------------- prep: degree histogram ----------------
__global__ void hist_kernel(const int* __restrict__ ei, int* __restrict__ deg) {
  int e = blockIdx.x * 256 + threadIdx.x;
  int d = ei[EE + e]; d = min(max(d, 0), NN - 1);
  atomicAdd(&deg[d], 1);
}

// ---------------- scans ----------------
__global__ void scan1(const int* __restrict__ deg, int* __restrict__ rows,
                      int* __restrict__ bsum) {
  __shared__ int s[256];
  int t = threadIdx.x, b = blockIdx.x, i = b * 256 + t;
  int v = deg[i];
  s[t] = v; __syncthreads();
  for (int off = 1; off < 256; off <<= 1) {
    int x = (t >= off) ? s[t - off] : 0; __syncthreads();
    s[t] += x; __syncthreads();
  }
  rows[i] = s[t] - v;
  if (t == 255) bsum[b] = s[255];
}
__global__ void scan2(int* __restrict__ bsum) {
  __shared__ int s[256];
  int t = threadIdx.x;
  int v = bsum[t];
  s[t] = v; __syncthreads();
  for (int off = 1; off < 256; off <<= 1) {
    int x = (t >= off) ? s[t - off] : 0; __syncthreads();
    s[t] += x; __syncthreads();
  }
  bsum[t] = s[t] - v;
}
__global__ void scan3(int* __restrict__ rows, const int* __restrict__ bsum,
                      int* __restrict__ cursor) {
  int t = threadIdx.x, b = blockIdx.x, i = b * 256 + t;
  int v = rows[i] + bsum[b];
  rows[i] = v;
  cursor[i] = v;
  if (i == NN - 1) rows[NN] = EE;
}

// ---------------- fill CSR rows ----------------
__global__ void fill_kernel(const int* __restrict__ ei, const float* __restrict__ pos,
                            int* __restrict__ cursor, u32* __restrict__ cr) {
  int e = blockIdx.x * 256 + threadIdx.x;
  int src = ei[e];      src = min(max(src, 0), NN - 1);
  int dst = ei[EE + e]; dst = min(max(dst, 0), NN - 1);
  float2 p = ((const float2*)pos)[e];
  float fl0 = floorf(p.x), fl1 = floorf(p.y);
  float f0 = p.x - fl0, f1 = p.y - fl1;
  int b0 = (int)fl0, b1 = (int)fl1;
  float w0[3] = { 0.5f*(1.f-f0)*(1.f-f0), -f0*f0+f0+0.5f, 0.5f*f0*f0 };
  float w1[3] = { 0.5f*(1.f-f1)*(1.f-f1), -f1*f1+f1+0.5f, 0.5f*f1*f1 };
  int i0[3], i1[3];
#pragma unroll
  for (int s = 0; s < 3; ++s) {
    i0[s] = min(max(b0 + s, 0), KS - 1);
    i1[s] = min(max(b1 + s, 0), KS - 1);
  }
  float c[9] = {0,0,0,0,0,0,0,0,0};
#pragma unroll
  for (int s0 = 0; s0 < 3; ++s0)
#pragma unroll
    for (int s1 = 0; s1 < 3; ++s1)
      c[i0[s0] + KS * i1[s1]] += w0[s0] * w1[s1];
  u16 h[9];
#pragma unroll
  for (int k = 0; k < 9; ++k) h[k] = f2bf(c[k]);
  int slot = atomicAdd(&cursor[dst], 1);
  slot = min(max(slot, 0), EE - 1);
  size_t b = (size_t)slot * 5;
  cr[b + 0] = (u32)(u16)src | ((u32)h[0] << 16);
  cr[b + 1] = (u32)h[1] | ((u32)h[2] << 16);
  cr[b + 2] = (u32)h[3] | ((u32)h[4] << 16);
  cr[b + 3] = (u32)h[5] | ((u32)h[6] << 16);
  cr[b + 4] = (u32)h[7] | ((u32)h[8] << 16);
}

// ---------------- build packed B matrices ----------------
struct BDesc { const float* W; int dstOff, i0, INW, OUT, K, isRoot; };
struct BDescs { BDesc d[18]; };

__global__ void build_b(BDescs ds, u16* __restrict__ bmat) {
  BDesc d = ds.d[blockIdx.y];
  int idx = blockIdx.x * 256 + threadIdx.x;
  int elems = d.K * d.OUT;
  if (idx >= elems) return;
  int o = idx / d.K, r = idx - o * d.K;
  float v;
  if (d.isRoot) {
    v = (r < d.INW) ? d.W[(size_t)(d.i0 + r) * d.OUT + o] : 0.f;
  } else {
    int kk = r >> 5, ii = r & 31;
    int i = d.i0 + ii;
    v = (i < d.INW) ? d.W[((size_t)kk * d.INW + i) * d.OUT + o] : 0.f;
  }
  bmat[(size_t)d.dstOff + (size_t)o * d.K + r] = f2bf(v);
}

// ---------------- fused layer, v6: single-walk + cross-layer partial in/out ----------------
// block = 256 thr = 4 waves sharing ONE 8-node tile; 8 blocks/CU = 32 waves/CU.
// mode 0: full-wave; lane = feature; cr row WAVE-UNIFORM -> coeffs scalarized.
// mode 1: half-wave; per-lane coeff decode.
// pout: while agg tile is in LDS, also contract it against a LATER layer's
//       weight chunk (e.g. enc2's agg_h2 @ W_d0[64:128]) and store raw f32
//       partial -> that layer then skips an entire gather pass (request law).
struct PD { const u16* src; const u16* src2; int IN, IN2, mode, bOffA, ncA, bOffB, ncB; };
struct RD { const u16* src; int astride, ksteps, bOff; };
struct FArgs { PD ch; RD rt[2]; int nrt; const float* bias; u16* dst;
               const float* pin; float* pout; int poutW, pBOffA, pncA; };

#define NSTRIDE 1192   // u16 per node row: 4 chunks x 296 + 8 pad

#define DECODE9U(Q0)                                              \
    u32 q1 = __builtin_amdgcn_readfirstlane(p[1]);                \
    u32 q2 = __builtin_amdgcn_readfirstlane(p[2]);                \
    u32 q3 = __builtin_amdgcn_readfirstlane(p[3]);                \
    u32 q4 = __builtin_amdgcn_readfirstlane(p[4]);                \
    float c0 = bf2f((u16)((Q0) >> 16));                           \
    float c1 = bf2f((u16)(q1 & 0xffffu)), c2 = bf2f((u16)(q1 >> 16)); \
    float c3 = bf2f((u16)(q2 & 0xffffu)), c4 = bf2f((u16)(q2 >> 16)); \
    float c5 = bf2f((u16)(q3 & 0xffffu)), c6 = bf2f((u16)(q3 >> 16)); \
    float c7 = bf2f((u16)(q4 & 0xffffu)), c8 = bf2f((u16)(q4 >> 16));

#define DECODE9V(Q0)                                              \
    u32 q1 = p[1], q2 = p[2], q3 = p[3], q4 = p[4];               \
    float c0 = bf2f((u16)((Q0) >> 16));                           \
    float c1 = bf2f((u16)(q1 & 0xffffu)), c2 = bf2f((u16)(q1 >> 16)); \
    float c3 = bf2f((u16)(q2 & 0xffffu)), c4 = bf2f((u16)(q2 >> 16)); \
    float c5 = bf2f((u16)(q3 & 0xffffu)), c6 = bf2f((u16)(q3 >> 16)); \
    float c7 = bf2f((u16)(q4 & 0xffffu)), c8 = bf2f((u16)(q4 >> 16));

#define ACC9(DST, XV) do {                                        \
    DST[0] = fmaf(c0, (XV), DST[0]); DST[1] = fmaf(c1, (XV), DST[1]); \
    DST[2] = fmaf(c2, (XV), DST[2]); DST[3] = fmaf(c3, (XV), DST[3]); \
    DST[4] = fmaf(c4, (XV), DST[4]); DST[5] = fmaf(c5, (XV), DST[5]); \
    DST[6] = fmaf(c6, (XV), DST[6]); DST[7] = fmaf(c7, (XV), DST[7]); \
    DST[8] = fmaf(c8, (XV), DST[8]); } while (0)

template <int OUT>
__global__ __launch_bounds__(256, 8) void fused_layer(FArgs fa, const u32* __restrict__ cr,
                                                      const int* __restrict__ rows,
                                                      const u16* __restrict__ bmat) {
  __shared__ u16 aggl[8 * NSTRIDE];
  constexpr int NT = OUT / 16;
  const int tid = threadIdx.x;
  const int wave = tid >> 6, lane = tid & 63;
  const int quad = lane >> 4, l16 = lane & 15;
  const int l = lane & 31, half = lane >> 5;
  const int nb = blockIdx.x * 8;

  const PD d = fa.ch;
  if (d.mode == 0) {
    // ---- full-wave: lane = feature; optional dual-line; 4-edge groups ----
    const bool has2 = d.src2 != nullptr;
    const bool v2 = has2 && (lane < d.IN2);
    const u16* sp  = d.src + lane;
    const u16* sp2 = has2 ? d.src2 + (v2 ? lane : 0) : nullptr;
    const int st2 = d.IN2;
    const int cslot  = half * 296 + l;           // chunks 0-1
    const int cslotB = 2 * 296 + half * 296 + l; // chunks 2-3
    for (int nn = 0; nn < 2; ++nn) {
      const int node = nb + wave * 2 + nn;
      const int rs = rows[node], re = rows[node + 1];
      float a[9] = {0,0,0,0,0,0,0,0,0};
      float b9[9] = {0,0,0,0,0,0,0,0,0};
      int r = rs;
      for (; r + 3 < re; r += 4) {
        u32 w0[4]; float xv[4], yv[4];
#pragma unroll
        for (int g = 0; g < 4; ++g) w0[g] = cr[(size_t)(r + g) * 5];
#pragma unroll
        for (int g = 0; g < 4; ++g)
          xv[g] = bf2f(sp[(size_t)(w0[g] & 0xffffu) * 64]);
        if (has2) {
#pragma unroll
          for (int g = 0; g < 4; ++g)
            yv[g] = v2 ? bf2f(sp2[(size_t)(w0[g] & 0xffffu) * st2]) : 0.f;
        }
#pragma unroll
        for (int g = 0; g < 4; ++g) {
          const u32* p = cr + (size_t)(r + g) * 5;
          u32 q0 = __builtin_amdgcn_readfirstlane(w0[g]);
          DECODE9U(q0);
          ACC9(a, xv[g]);
          if (has2) ACC9(b9, yv[g]);
        }
      }
      for (; r < re; ++r) {
        const u32* p = cr + (size_t)r * 5;
        u32 w0 = p[0];
        float xv = bf2f(sp[(size_t)(w0 & 0xffffu) * 64]);
        float yv = 0.f;
        if (has2) yv = v2 ? bf2f(sp2[(size_t)(w0 & 0xffffu) * st2]) : 0.f;
        u32 q0 = __builtin_amdgcn_readfirstlane(w0);
        DECODE9U(q0);
        ACC9(a, xv);
        if (has2) ACC9(b9, yv);
      }
      const float inv = 1.f / fmaxf((float)(re - rs), 1.f);
      const int row = wave * 2 + nn;
#pragma unroll
      for (int k = 0; k < 9; ++k)
        aggl[row * NSTRIDE + cslot + k * 32] = f2bf(a[k] * inv);
      if (has2) {
#pragma unroll
        for (int k = 0; k < 9; ++k)
          aggl[row * NSTRIDE + cslotB + k * 32] = f2bf(b9[k] * inv);
      }
    }
  } else {
    // ---- half-wave: lane%32 = feature, 2 edges in flight (per-lane decode) ----
    const int i = l;
    const bool valid = i < d.IN;
    const u16* sp = d.src + i;
    const int IN = d.IN;
    for (int nn = 0; nn < 2; ++nn) {
      const int node = nb + wave * 2 + nn;
      const int rs = rows[node], re = rows[node + 1];
      float a[9] = {0,0,0,0,0,0,0,0,0};
      int r = rs + half;
      for (; r + 2 < re; r += 4) {
        u32 w0[2]; float xv[2];
#pragma unroll
        for (int g = 0; g < 2; ++g) w0[g] = cr[(size_t)(r + 2 * g) * 5];
#pragma unroll
        for (int g = 0; g < 2; ++g)
          xv[g] = valid ? bf2f(sp[(size_t)(w0[g] & 0xffffu) * IN]) : 0.f;
#pragma unroll
        for (int g = 0; g < 2; ++g) {
          const u32* p = cr + (size_t)(r + 2 * g) * 5;
          u32 q0 = w0[g];
          DECODE9V(q0);
          ACC9(a, xv[g]);
        }
      }
      for (; r < re; r += 2) {
        const u32* p = cr + (size_t)r * 5;
        u32 q0 = p[0];
        float xv = valid ? bf2f(sp[(size_t)(q0 & 0xffffu) * IN]) : 0.f;
        DECODE9V(q0);
        ACC9(a, xv);
      }
#pragma unroll
      for (int k = 0; k < 9; ++k) a[k] += __shfl_xor(a[k], 32);
      const float inv = 1.f / fmaxf((float)(re - rs), 1.f);
      if (half == 0) {
#pragma unroll
        for (int k = 0; k < 9; ++k)
          aggl[(wave * 2 + nn) * NSTRIDE + k * 32 + l] = f2bf(a[k] * inv);
      }
    }
  }
  __syncthreads();

  // ---- partial-out: contract agg tile against a later layer's weight chunk ----
  if (fa.pout && wave < (fa.poutW >> 4)) {
    f32x4 P = (f32x4){0.f, 0.f, 0.f, 0.f};
    for (int cc = 0; cc < fa.pncA; ++cc) {
      const u16* Bp = bmat + fa.pBOffA + cc * 288 * fa.poutW;
      for (int ks = 0; ks < 9; ++ks) {
        bf16x8 av = *(const bf16x8*)&aggl[l16 * NSTRIDE + cc * 296 + ks * 32 + quad * 8];
        bf16x8 bv = *(const bf16x8*)(Bp + ((size_t)(wave * 16 + l16) * 9 + ks) * 32 + quad * 8);
        P = __builtin_amdgcn_mfma_f32_16x16x32_bf16(av, bv, P, 0, 0, 0);
      }
    }
    if (quad < 2) {
#pragma unroll
      for (int r = 0; r < 4; ++r)
        fa.pout[(size_t)(nb + quad * 4 + r) * fa.poutW + wave * 16 + l16] = P[r];
    }
  }

  if (wave < NT) {
    f32x4 C = (f32x4){0.f, 0.f, 0.f, 0.f};
    for (int cc = 0; cc < d.ncA; ++cc) {
      const u16* Bp = bmat + d.bOffA + cc * 288 * OUT;
      for (int ks = 0; ks < 9; ++ks) {
        bf16x8 av = *(const bf16x8*)&aggl[l16 * NSTRIDE + cc * 296 + ks * 32 + quad * 8];
        bf16x8 bv = *(const bf16x8*)(Bp + ((size_t)(wave * 16 + l16) * 9 + ks) * 32 + quad * 8);
        C = __builtin_amdgcn_mfma_f32_16x16x32_bf16(av, bv, C, 0, 0, 0);
      }
    }
    for (int cc = 0; cc < d.ncB; ++cc) {
      const u16* Bp = bmat + d.bOffB + cc * 288 * OUT;
      for (int ks = 0; ks < 9; ++ks) {
        bf16x8 av = *(const bf16x8*)&aggl[l16 * NSTRIDE + (2 + cc) * 296 + ks * 32 + quad * 8];
        bf16x8 bv = *(const bf16x8*)(Bp + ((size_t)(wave * 16 + l16) * 9 + ks) * 32 + quad * 8);
        C = __builtin_amdgcn_mfma_f32_16x16x32_bf16(av, bv, C, 0, 0, 0);
      }
    }
    for (int rx = 0; rx < fa.nrt; ++rx) {
      const RD rd = fa.rt[rx];
      for (int ks = 0; ks < rd.ksteps; ++ks) {
        bf16x8 av = *(const bf16x8*)(rd.src + (size_t)(nb + l16) * rd.astride + ks * 32 + quad * 8);
        bf16x8 bv = *(const bf16x8*)(bmat + rd.bOff
                     + ((size_t)(wave * 16 + l16) * rd.ksteps + ks) * 32 + quad * 8);
        C = __builtin_amdgcn_mfma_f32_16x16x32_bf16(av, bv, C, 0, 0, 0);
      }
    }
    if (quad < 2) {
#pragma unroll
      for (int r = 0; r < 4; ++r) {
        int node = nb + quad * 4 + r;
        int o = wave * 16 + l16;
        float v = C[r] + fa.bias[o];
        if (fa.pin) v += fa.pin[(size_t)node * OUT + o];
        v = fminf(fmaxf(v, 0.f), 6.f);
        fa.dst[(size_t)node * OUT + o] = f2bf(v);
      }
    }
  }
}

// ---------------- final MLP ----------------
__global__ __launch_bounds__(256) void mlp1(const u16* __restrict__ d1,
                                            const float* __restrict__ w1,
                                            float* __restrict__ hbuf) {
  __shared__ __align__(16) u16 bt[128 * 136];
  const int tid = threadIdx.x;
  const int c0 = blockIdx.x * 128;
  for (int idx = tid; idx < 16384; idx += 256) {
    int k = idx >> 7, col = idx & 127;
    bt[col * 136 + k] = f2bf(w1[(size_t)(c0 + k) * 128 + col]);
  }
  __syncthreads();
  const int wave = tid >> 6, lane = tid & 63;
  const int quad = lane >> 4, l16 = lane & 15;
  f32x4 C[8];
#pragma unroll
  for (int nt = 0; nt < 8; ++nt) C[nt] = (f32x4){0.f, 0.f, 0.f, 0.f};
  for (int ks = 0; ks < 4; ++ks) {
    bf16x8 av = *(const bf16x8*)(d1 + (size_t)(wave * 16 + l16) * 32768 + c0 + ks * 32 + quad * 8);
#pragma unroll
    for (int nt = 0; nt < 8; ++nt) {
      bf16x8 bv = *(const bf16x8*)&bt[(nt * 16 + l16) * 136 + ks * 32 + quad * 8];
      C[nt] = __builtin_amdgcn_mfma_f32_16x16x32_bf16(av, bv, C[nt], 0, 0, 0);
    }
  }
#pragma unroll
  for (int nt = 0; nt < 8; ++nt)
#pragma unroll
    for (int r = 0; r < 4; ++r) {
      int g = wave * 16 + quad * 4 + r;
      int o = nt * 16 + l16;
      atomicAdd(&hbuf[g * 128 + o], C[nt][r]);
    }
}

__global__ void mlp2(const float* __restrict__ hbuf, const float* __restrict__ b1,
                     const float* __restrict__ w2, const float* __restrict__ b2,
                     float* __restrict__ out) {
  const int t = threadIdx.x;
  if (t >= BB * 3) return;
  const int g = t / 3, c = t % 3;
  float acc = b2[c];
  for (int j = 0; j < 128; ++j) {
    float h = fmaxf(hbuf[g * 128 + j] + b1[j], 0.f);
    acc = fmaf(h, w2[j * 3 + c], acc);
  }
  out[g * 3 + c] = acc;
}

// ---------------- launch ----------------
extern "C" void kernel_launch(void* const* d_in, const int* in_sizes, int n_in,
                              void* d_out, int out_size, void* d_ws, size_t ws_size,
                              hipStream_t stream) {
  const float* x   = (const float*)d_in[0];
  const int*   ei  = (const int*)d_in[1];
  const float* pos = (const float*)d_in[2];

  char* base = (char*)d_ws;
  u32*   cr     = (u32*)(base + O_CR);
  int*   rows   = (int*)(base + O_ROWS);
  int*   cursor = (int*)(base + O_CURS);
  int*   bsum   = (int*)(base + O_BSUM);
  u16*   bmat   = (u16*)(base + O_BMAT);
  u16*   xb     = (u16*)(base + O_XB);
  u16*   h1     = (u16*)(base + O_H1);
  u16*   h2     = (u16*)(base + O_H2);
  u16*   h3     = (u16*)(base + O_H3);
  u16*   d0     = (u16*)(base + O_D0);
  u16*   d1     = (u16*)(base + O_D1);
  float* hbuf   = (float*)(base + O_HBUF);
  int*   deg    = (int*)(base + O_DEG);
  float* pd0    = (float*)(base + O_PD0);
  float* pd1    = (float*)(base + O_PD1);

  hipMemsetAsync(base + O_HBUF, 0, 32768 + 262144, stream);   // hbuf + deg

  cvt_x<<<NN * 16 / 256, 256, 0, stream>>>(x, xb);
  hist_kernel<<<EE / 256, 256, 0, stream>>>(ei, deg);
  scan1<<<256, 256, 0, stream>>>(deg, rows, bsum);
  scan2<<<1, 256, 0, stream>>>(bsum);
  scan3<<<256, 256, 0, stream>>>(rows, bsum, cursor);
  fill_kernel<<<EE / 256, 256, 0, stream>>>(ei, pos, cursor, cr);

  const float* W_e0 = (const float*)d_in[4];
  const float* R_e0 = (const float*)d_in[5];
  const float* B_e0 = (const float*)d_in[6];
  const float* W_e1 = (const float*)d_in[7];
  const float* R_e1 = (const float*)d_in[8];
  const float* B_e1 = (const float*)d_in[9];
  const float* W_e2 = (const float*)d_in[10];
  const float* R_e2 = (const float*)d_in[11];
  const float* B_e2 = (const float*)d_in[12];
  const float* W_d0 = (const float*)d_in[13];
  const float* R_d0 = (const float*)d_in[14];
  const float* B_d0 = (const float*)d_in[15];
  const float* W_d1 = (const float*)d_in[16];
  const float* R_d1 = (const float*)d_in[17];
  const float* B_d1 = (const float*)d_in[18];

  BDescs ds;
  ds.d[0]  = { W_e0, 0,      0,  16,  32, 288, 0 };
  ds.d[1]  = { W_e1, 9216,   0,  32,  64, 288, 0 };
  ds.d[2]  = { W_e2, 27648,  0,  64,  64, 288, 0 };
  ds.d[3]  = { W_e2, 46080,  32, 64,  64, 288, 0 };
  ds.d[4]  = { W_d0, 64512,  0,  128, 64, 288, 0 };
  ds.d[5]  = { W_d0, 82944,  32, 128, 64, 288, 0 };
  ds.d[6]  = { W_d0, 101376, 64, 128, 64, 288, 0 };
  ds.d[7]  = { W_d0, 119808, 96, 128, 64, 288, 0 };
  ds.d[8]  = { W_d1, 138240, 0,  96,  32, 288, 0 };
  ds.d[9]  = { W_d1, 147456, 32, 96,  32, 288, 0 };
  ds.d[10] = { W_d1, 156672, 64, 96,  32, 288, 0 };
  ds.d[11] = { R_e0, 165888, 0,  16, 32, 32, 1 };
  ds.d[12] = { R_e1, 166912, 0,  32, 64, 32, 1 };
  ds.d[13] = { R_e2, 168960, 0,  64, 64, 64, 1 };
  ds.d[14] = { R_d0, 173056, 0,  64, 64, 64, 1 };
  ds.d[15] = { R_d0, 177152, 64, 64, 64, 64, 1 };
  ds.d[16] = { R_d1, 181248, 0,  64, 32, 64, 1 };
  ds.d[17] = { R_d1, 183296, 64, 32, 32, 32, 1 };
  build_b<<<dim3(72, 18), 256, 0, stream>>>(ds, bmat);

  const int FG = NN / 8;   // 8192 blocks x 4 waves, 8 nodes/block

  // enc0: gather x (IN=16, half-wave) + root
  FArgs fe0 = { {xb, nullptr, 16, 0, 1, 0, 1, 0, 0},
                { {xb, 16, 1, 165888}, {} }, 1, B_e0, h1,
                nullptr, nullptr, 0, 0, 0 };
  fused_layer<32><<<FG, 256, 0, stream>>>(fe0, cr, rows, bmat);

  // enc1: gather h1 + root; ALSO contract agg_h1 @ W_d1[64:96] -> pd1 (dec1 partial)
  FArgs fe1 = { {h1, nullptr, 32, 0, 1, 9216, 1, 0, 0},
                { {h1, 32, 1, 166912}, {} }, 1, B_e1, h2,
                nullptr, pd1, 32, 156672, 1 };
  fused_layer<64><<<FG, 256, 0, stream>>>(fe1, cr, rows, bmat);

  // enc2: gather h2 + root; ALSO contract agg_h2 @ W_d0[64:128] -> pd0 (dec0 partial)
  FArgs fe2 = { {h2, nullptr, 64, 0, 0, 27648, 2, 0, 0},
                { {h2, 64, 2, 168960}, {} }, 1, B_e2, h3,
                nullptr, pd0, 64, 101376, 2 };
  fused_layer<64><<<FG, 256, 0, stream>>>(fe2, cr, rows, bmat);

  // dec0: gather h3 ONLY (1 line/edge) + pd0 partial + roots h3, h2
  FArgs fd0 = { {h3, nullptr, 64, 0, 0, 64512, 2, 0, 0},
                { {h3, 64, 2, 173056}, {h2, 64, 2, 177152} }, 2, B_d0, d0,
                pd0, nullptr, 0, 0, 0 };
  fused_layer<64><<<FG, 256, 0, stream>>>(fd0, cr, rows, bmat);

  // dec1: gather d0 ONLY (1 line/edge) + pd1 partial + roots d0, h1
  FArgs fd1 = { {d0, nullptr, 64, 0, 0, 138240, 2, 0, 0},
                { {d0, 64, 2, 181248}, {h1, 32, 1, 183296} }, 2, B_d1, d1,
                pd1, nullptr, 0, 0, 0 };
  fused_layer<32><<<FG, 256, 0, stream>>>(fd1, cr, rows, bmat);

  mlp1<<<256, 256, 0, stream>>>(d1, (const float*)d_in[19], hbuf);
  mlp2<<<1, 256, 0, stream>>>(hbuf, (const float*)d_in[20], (const float*)d_in[21],
                              (const float*)d_in[22], (float*)d_out);
}

// Round 15
// 610.158 us; speedup vs baseline: 1.2026x; 1.0072x over previous
//
#include <hip/hip_runtime.h>

#define KS 3
#define NN 65536
#define EE 524288
#define BB 64

typedef unsigned short u16;
typedef unsigned int u32;

typedef __attribute__((ext_vector_type(8))) short bf16x8;
typedef __attribute__((ext_vector_type(4))) float f32x4;

__device__ __forceinline__ float bf2f(u16 u) {
  union { u32 i; float f; } v; v.i = ((u32)u) << 16; return v.f;
}
__device__ __forceinline__ u16 f2bf(float f) {
  union { float f; u32 i; } v; v.f = f;
  u32 x = v.i;
  x += 0x7fffu + ((x >> 16) & 1u);   // RNE
  return (u16)(x >> 16);
}

// ---------------- ws byte offsets (peak ~59.9 MB) ----------------
static const size_t O_CR   = 0;                    // E x 5 u32
static const size_t O_ROWS = 10485760;             // (N+1) i32, padded 262,400
static const size_t O_CURS = 10748160;             // N i32
static const size_t O_BSUM = 11010304;             // 256 i32 pad 1024
static const size_t O_BMAT = 11011328;             // packed B mats 368,640
static const size_t O_XB   = 11379968;             // N*16 bf16 + 64 slack
static const size_t O_H1   = 13477184;             // N*32 bf16
static const size_t O_H2   = 17671488;             // N*64 bf16
static const size_t O_H3   = 26060096;             // N*64 bf16
static const size_t O_D0   = 34448704;             // N*64 bf16
static const size_t O_D1   = 42837312;             // N*32 bf16
static const size_t O_HBUF = 47031616;             // 64*128 f32
static const size_t O_DEG  = 47064384;             // N i32
static const size_t O_PD0  = 47326528;             // N*64 bf16 = 8,388,608 (enc2 -> dec0 partial)
static const size_t O_PD1  = 55715136;             // N*32 bf16 = 4,194,304 (enc1 -> dec1 partial)
// end = 59,909,440

// ---------------- prep0: x f32 -> bf16 AND degree histogram (merged) ----------------
__global__ void prep0(const float* __restrict__ x, u16* __restrict__ xb,
                      const int* __restrict__ ei, int* __restrict__ deg) {
  int i = blockIdx.x * 256 + threadIdx.x;      // grid covers N*16 = 1,048,576
  xb[i] = f2bf(x[i]);
  if (i < EE) {
    int d = ei[EE + i]; d = min(max(d, 0), NN - 1);
    atomicAdd(&deg[d], 1);
  }
}

// ---------------- scans ----------------
__global__ void scan1(const int* __restrict__ deg, int* __restrict__ rows,
                      int* __restrict__ bsum) {
  __shared__ int s[256];
  int t = threadIdx.x, b = blockIdx.x, i = b * 256 + t;
  int v = deg[i];
  s[t] = v; __syncthreads();
  for (int off = 1; off < 256; off <<= 1) {
    int x = (t >= off) ? s[t - off] : 0; __syncthreads();
    s[t] += x; __syncthreads();
  }
  rows[i] = s[t] - v;
  if (t == 255) bsum[b] = s[255];
}
__global__ void scan2(int* __restrict__ bsum) {
  __shared__ int s[256];
  int t = threadIdx.x;
  int v = bsum[t];
  s[t] = v; __syncthreads();
  for (int off = 1; off < 256; off <<= 1) {
    int x = (t >= off) ? s[t - off] : 0; __syncthreads();
    s[t] += x; __syncthreads();
  }
  bsum[t] = s[t] - v;
}
__global__ void scan3(int* __restrict__ rows, const int* __restrict__ bsum,
                      int* __restrict__ cursor) {
  int t = threadIdx.x, b = blockIdx.x, i = b * 256 + t;
  int v = rows[i] + bsum[b];
  rows[i] = v;
  cursor[i] = v;
  if (i == NN - 1) rows[NN] = EE;
}

// ---------------- fill CSR rows ----------------
__global__ void fill_kernel(const int* __restrict__ ei, const float* __restrict__ pos,
                            int* __restrict__ cursor, u32* __restrict__ cr) {
  int e = blockIdx.x * 256 + threadIdx.x;
  int src = ei[e];      src = min(max(src, 0), NN - 1);
  int dst = ei[EE + e]; dst = min(max(dst, 0), NN - 1);
  float2 p = ((const float2*)pos)[e];
  float fl0 = floorf(p.x), fl1 = floorf(p.y);
  float f0 = p.x - fl0, f1 = p.y - fl1;
  int b0 = (int)fl0, b1 = (int)fl1;
  float w0[3] = { 0.5f*(1.f-f0)*(1.f-f0), -f0*f0+f0+0.5f, 0.5f*f0*f0 };
  float w1[3] = { 0.5f*(1.f-f1)*(1.f-f1), -f1*f1+f1+0.5f, 0.5f*f1*f1 };
  int i0[3], i1[3];
#pragma unroll
  for (int s = 0; s < 3; ++s) {
    i0[s] = min(max(b0 + s, 0), KS - 1);
    i1[s] = min(max(b1 + s, 0), KS - 1);
  }
  float c[9] = {0,0,0,0,0,0,0,0,0};
#pragma unroll
  for (int s0 = 0; s0 < 3; ++s0)
#pragma unroll
    for (int s1 = 0; s1 < 3; ++s1)
      c[i0[s0] + KS * i1[s1]] += w0[s0] * w1[s1];
  u16 h[9];
#pragma unroll
  for (int k = 0; k < 9; ++k) h[k] = f2bf(c[k]);
  int slot = atomicAdd(&cursor[dst], 1);
  slot = min(max(slot, 0), EE - 1);
  size_t b = (size_t)slot * 5;
  cr[b + 0] = (u32)(u16)src | ((u32)h[0] << 16);
  cr[b + 1] = (u32)h[1] | ((u32)h[2] << 16);
  cr[b + 2] = (u32)h[3] | ((u32)h[4] << 16);
  cr[b + 3] = (u32)h[5] | ((u32)h[6] << 16);
  cr[b + 4] = (u32)h[7] | ((u32)h[8] << 16);
}

// ---------------- build packed B matrices ----------------
struct BDesc { const float* W; int dstOff, i0, INW, OUT, K, isRoot; };
struct BDescs { BDesc d[18]; };

__global__ void build_b(BDescs ds, u16* __restrict__ bmat) {
  BDesc d = ds.d[blockIdx.y];
  int idx = blockIdx.x * 256 + threadIdx.x;
  int elems = d.K * d.OUT;
  if (idx >= elems) return;
  int o = idx / d.K, r = idx - o * d.K;
  float v;
  if (d.isRoot) {
    v = (r < d.INW) ? d.W[(size_t)(d.i0 + r) * d.OUT + o] : 0.f;
  } else {
    int kk = r >> 5, ii = r & 31;
    int i = d.i0 + ii;
    v = (i < d.INW) ? d.W[((size_t)kk * d.INW + i) * d.OUT + o] : 0.f;
  }
  bmat[(size_t)d.dstOff + (size_t)o * d.K + r] = f2bf(v);
}

// ---------------- fused layer, v7: single-walk + bf16 cross-layer partials ----------------
struct PD { const u16* src; const u16* src2; int IN, IN2, mode, bOffA, ncA, bOffB, ncB; };
struct RD { const u16* src; int astride, ksteps, bOff; };
struct FArgs { PD ch; RD rt[2]; int nrt; const float* bias; u16* dst;
               const u16* pin; u16* pout; int poutW, pBOffA, pncA; };

#define NSTRIDE 1192   // u16 per node row: 4 chunks x 296 + 8 pad

#define DECODE9U(Q0)                                              \
    u32 q1 = __builtin_amdgcn_readfirstlane(p[1]);                \
    u32 q2 = __builtin_amdgcn_readfirstlane(p[2]);                \
    u32 q3 = __builtin_amdgcn_readfirstlane(p[3]);                \
    u32 q4 = __builtin_amdgcn_readfirstlane(p[4]);                \
    float c0 = bf2f((u16)((Q0) >> 16));                           \
    float c1 = bf2f((u16)(q1 & 0xffffu)), c2 = bf2f((u16)(q1 >> 16)); \
    float c3 = bf2f((u16)(q2 & 0xffffu)), c4 = bf2f((u16)(q2 >> 16)); \
    float c5 = bf2f((u16)(q3 & 0xffffu)), c6 = bf2f((u16)(q3 >> 16)); \
    float c7 = bf2f((u16)(q4 & 0xffffu)), c8 = bf2f((u16)(q4 >> 16));

#define DECODE9V(Q0)                                              \
    u32 q1 = p[1], q2 = p[2], q3 = p[3], q4 = p[4];               \
    float c0 = bf2f((u16)((Q0) >> 16));                           \
    float c1 = bf2f((u16)(q1 & 0xffffu)), c2 = bf2f((u16)(q1 >> 16)); \
    float c3 = bf2f((u16)(q2 & 0xffffu)), c4 = bf2f((u16)(q2 >> 16)); \
    float c5 = bf2f((u16)(q3 & 0xffffu)), c6 = bf2f((u16)(q3 >> 16)); \
    float c7 = bf2f((u16)(q4 & 0xffffu)), c8 = bf2f((u16)(q4 >> 16));

#define ACC9(DST, XV) do {                                        \
    DST[0] = fmaf(c0, (XV), DST[0]); DST[1] = fmaf(c1, (XV), DST[1]); \
    DST[2] = fmaf(c2, (XV), DST[2]); DST[3] = fmaf(c3, (XV), DST[3]); \
    DST[4] = fmaf(c4, (XV), DST[4]); DST[5] = fmaf(c5, (XV), DST[5]); \
    DST[6] = fmaf(c6, (XV), DST[6]); DST[7] = fmaf(c7, (XV), DST[7]); \
    DST[8] = fmaf(c8, (XV), DST[8]); } while (0)

template <int OUT>
__global__ __launch_bounds__(256, 8) void fused_layer(FArgs fa, const u32* __restrict__ cr,
                                                      const int* __restrict__ rows,
                                                      const u16* __restrict__ bmat) {
  __shared__ u16 aggl[8 * NSTRIDE];
  constexpr int NT = OUT / 16;
  const int tid = threadIdx.x;
  const int wave = tid >> 6, lane = tid & 63;
  const int quad = lane >> 4, l16 = lane & 15;
  const int l = lane & 31, half = lane >> 5;
  const int nb = blockIdx.x * 8;

  const PD d = fa.ch;
  if (d.mode == 0) {
    const bool has2 = d.src2 != nullptr;
    const bool v2 = has2 && (lane < d.IN2);
    const u16* sp  = d.src + lane;
    const u16* sp2 = has2 ? d.src2 + (v2 ? lane : 0) : nullptr;
    const int st2 = d.IN2;
    const int cslot  = half * 296 + l;
    const int cslotB = 2 * 296 + half * 296 + l;
    for (int nn = 0; nn < 2; ++nn) {
      const int node = nb + wave * 2 + nn;
      const int rs = rows[node], re = rows[node + 1];
      float a[9] = {0,0,0,0,0,0,0,0,0};
      float b9[9] = {0,0,0,0,0,0,0,0,0};
      int r = rs;
      for (; r + 3 < re; r += 4) {
        u32 w0[4]; float xv[4], yv[4];
#pragma unroll
        for (int g = 0; g < 4; ++g) w0[g] = cr[(size_t)(r + g) * 5];
#pragma unroll
        for (int g = 0; g < 4; ++g)
          xv[g] = bf2f(sp[(size_t)(w0[g] & 0xffffu) * 64]);
        if (has2) {
#pragma unroll
          for (int g = 0; g < 4; ++g)
            yv[g] = v2 ? bf2f(sp2[(size_t)(w0[g] & 0xffffu) * st2]) : 0.f;
        }
#pragma unroll
        for (int g = 0; g < 4; ++g) {
          const u32* p = cr + (size_t)(r + g) * 5;
          u32 q0 = __builtin_amdgcn_readfirstlane(w0[g]);
          DECODE9U(q0);
          ACC9(a, xv[g]);
          if (has2) ACC9(b9, yv[g]);
        }
      }
      for (; r < re; ++r) {
        const u32* p = cr + (size_t)r * 5;
        u32 w0 = p[0];
        float xv = bf2f(sp[(size_t)(w0 & 0xffffu) * 64]);
        float yv = 0.f;
        if (has2) yv = v2 ? bf2f(sp2[(size_t)(w0 & 0xffffu) * st2]) : 0.f;
        u32 q0 = __builtin_amdgcn_readfirstlane(w0);
        DECODE9U(q0);
        ACC9(a, xv);
        if (has2) ACC9(b9, yv);
      }
      const float inv = 1.f / fmaxf((float)(re - rs), 1.f);
      const int row = wave * 2 + nn;
#pragma unroll
      for (int k = 0; k < 9; ++k)
        aggl[row * NSTRIDE + cslot + k * 32] = f2bf(a[k] * inv);
      if (has2) {
#pragma unroll
        for (int k = 0; k < 9; ++k)
          aggl[row * NSTRIDE + cslotB + k * 32] = f2bf(b9[k] * inv);
      }
    }
  } else {
    const int i = l;
    const bool valid = i < d.IN;
    const u16* sp = d.src + i;
    const int IN = d.IN;
    for (int nn = 0; nn < 2; ++nn) {
      const int node = nb + wave * 2 + nn;
      const int rs = rows[node], re = rows[node + 1];
      float a[9] = {0,0,0,0,0,0,0,0,0};
      int r = rs + half;
      for (; r + 2 < re; r += 4) {
        u32 w0[2]; float xv[2];
#pragma unroll
        for (int g = 0; g < 2; ++g) w0[g] = cr[(size_t)(r + 2 * g) * 5];
#pragma unroll
        for (int g = 0; g < 2; ++g)
          xv[g] = valid ? bf2f(sp[(size_t)(w0[g] & 0xffffu) * IN]) : 0.f;
#pragma unroll
        for (int g = 0; g < 2; ++g) {
          const u32* p = cr + (size_t)(r + 2 * g) * 5;
          u32 q0 = w0[g];
          DECODE9V(q0);
          ACC9(a, xv[g]);
        }
      }
      for (; r < re; r += 2) {
        const u32* p = cr + (size_t)r * 5;
        u32 q0 = p[0];
        float xv = valid ? bf2f(sp[(size_t)(q0 & 0xffffu) * IN]) : 0.f;
        DECODE9V(q0);
        ACC9(a, xv);
      }
#pragma unroll
      for (int k = 0; k < 9; ++k) a[k] += __shfl_xor(a[k], 32);
      const float inv = 1.f / fmaxf((float)(re - rs), 1.f);
      if (half == 0) {
#pragma unroll
        for (int k = 0; k < 9; ++k)
          aggl[(wave * 2 + nn) * NSTRIDE + k * 32 + l] = f2bf(a[k] * inv);
      }
    }
  }
  __syncthreads();

  // ---- partial-out: contract agg tile against a later layer's weight chunk (bf16 store) ----
  if (fa.pout && wave < (fa.poutW >> 4)) {
    f32x4 P = (f32x4){0.f, 0.f, 0.f, 0.f};
    for (int cc = 0; cc < fa.pncA; ++cc) {
      const u16* Bp = bmat + fa.pBOffA + cc * 288 * fa.poutW;
      for (int ks = 0; ks < 9; ++ks) {
        bf16x8 av = *(const bf16x8*)&aggl[l16 * NSTRIDE + cc * 296 + ks * 32 + quad * 8];
        bf16x8 bv = *(const bf16x8*)(Bp + ((size_t)(wave * 16 + l16) * 9 + ks) * 32 + quad * 8);
        P = __builtin_amdgcn_mfma_f32_16x16x32_bf16(av, bv, P, 0, 0, 0);
      }
    }
    if (quad < 2) {
#pragma unroll
      for (int r = 0; r < 4; ++r)
        fa.pout[(size_t)(nb + quad * 4 + r) * fa.poutW + wave * 16 + l16] = f2bf(P[r]);
    }
  }

  if (wave < NT) {
    f32x4 C = (f32x4){0.f, 0.f, 0.f, 0.f};
    for (int cc = 0; cc < d.ncA; ++cc) {
      const u16* Bp = bmat + d.bOffA + cc * 288 * OUT;
      for (int ks = 0; ks < 9; ++ks) {
        bf16x8 av = *(const bf16x8*)&aggl[l16 * NSTRIDE + cc * 296 + ks * 32 + quad * 8];
        bf16x8 bv = *(const bf16x8*)(Bp + ((size_t)(wave * 16 + l16) * 9 + ks) * 32 + quad * 8);
        C = __builtin_amdgcn_mfma_f32_16x16x32_bf16(av, bv, C, 0, 0, 0);
      }
    }
    for (int cc = 0; cc < d.ncB; ++cc) {
      const u16* Bp = bmat + d.bOffB + cc * 288 * OUT;
      for (int ks = 0; ks < 9; ++ks) {
        bf16x8 av = *(const bf16x8*)&aggl[l16 * NSTRIDE + (2 + cc) * 296 + ks * 32 + quad * 8];
        bf16x8 bv = *(const bf16x8*)(Bp + ((size_t)(wave * 16 + l16) * 9 + ks) * 32 + quad * 8);
        C = __builtin_amdgcn_mfma_f32_16x16x32_bf16(av, bv, C, 0, 0, 0);
      }
    }
    for (int rx = 0; rx < fa.nrt; ++rx) {
      const RD rd = fa.rt[rx];
      for (int ks = 0; ks < rd.ksteps; ++ks) {
        bf16x8 av = *(const bf16x8*)(rd.src + (size_t)(nb + l16) * rd.astride + ks * 32 + quad * 8);
        bf16x8 bv = *(const bf16x8*)(bmat + rd.bOff
                     + ((size_t)(wave * 16 + l16) * rd.ksteps + ks) * 32 + quad * 8);
        C = __builtin_amdgcn_mfma_f32_16x16x32_bf16(av, bv, C, 0, 0, 0);
      }
    }
    if (quad < 2) {
#pragma unroll
      for (int r = 0; r < 4; ++r) {
        int node = nb + quad * 4 + r;
        int o = wave * 16 + l16;
        float v = C[r] + fa.bias[o];
        if (fa.pin) v += bf2f(fa.pin[(size_t)node * OUT + o]);
        v = fminf(fmaxf(v, 0.f), 6.f);
        fa.dst[(size_t)node * OUT + o] = f2bf(v);
      }
    }
  }
}

// ---------------- final MLP ----------------
__global__ __launch_bounds__(256) void mlp1(const u16* __restrict__ d1,
                                            const float* __restrict__ w1,
                                            float* __restrict__ hbuf) {
  __shared__ __align__(16) u16 bt[128 * 136];
  const int tid = threadIdx.x;
  const int c0 = blockIdx.x * 128;
  for (int idx = tid; idx < 16384; idx += 256) {
    int k = idx >> 7, col = idx & 127;
    bt[col * 136 + k] = f2bf(w1[(size_t)(c0 + k) * 128 + col]);
  }
  __syncthreads();
  const int wave = tid >> 6, lane = tid & 63;
  const int quad = lane >> 4, l16 = lane & 15;
  f32x4 C[8];
#pragma unroll
  for (int nt = 0; nt < 8; ++nt) C[nt] = (f32x4){0.f, 0.f, 0.f, 0.f};
  for (int ks = 0; ks < 4; ++ks) {
    bf16x8 av = *(const bf16x8*)(d1 + (size_t)(wave * 16 + l16) * 32768 + c0 + ks * 32 + quad * 8);
#pragma unroll
    for (int nt = 0; nt < 8; ++nt) {
      bf16x8 bv = *(const bf16x8*)&bt[(nt * 16 + l16) * 136 + ks * 32 + quad * 8];
      C[nt] = __builtin_amdgcn_mfma_f32_16x16x32_bf16(av, bv, C[nt], 0, 0, 0);
    }
  }
#pragma unroll
  for (int nt = 0; nt < 8; ++nt)
#pragma unroll
    for (int r = 0; r < 4; ++r) {
      int g = wave * 16 + quad * 4 + r;
      int o = nt * 16 + l16;
      atomicAdd(&hbuf[g * 128 + o], C[nt][r]);
    }
}

__global__ void mlp2(const float* __restrict__ hbuf, const float* __restrict__ b1,
                     const float* __restrict__ w2, const float* __restrict__ b2,
                     float* __restrict__ out) {
  const int t = threadIdx.x;
  if (t >= BB * 3) return;
  const int g = t / 3, c = t % 3;
  float acc = b2[c];
  for (int j = 0; j < 128; ++j) {
    float h = fmaxf(hbuf[g * 128 + j] + b1[j], 0.f);
    acc = fmaf(h, w2[j * 3 + c], acc);
  }
  out[g * 3 + c] = acc;
}

// ---------------- launch ----------------
extern "C" void kernel_launch(void* const* d_in, const int* in_sizes, int n_in,
                              void* d_out, int out_size, void* d_ws, size_t ws_size,
                              hipStream_t stream) {
  const float* x   = (const float*)d_in[0];
  const int*   ei  = (const int*)d_in[1];
  const float* pos = (const float*)d_in[2];

  char* base = (char*)d_ws;
  u32*   cr     = (u32*)(base + O_CR);
  int*   rows   = (int*)(base + O_ROWS);
  int*   cursor = (int*)(base + O_CURS);
  int*   bsum   = (int*)(base + O_BSUM);
  u16*   bmat   = (u16*)(base + O_BMAT);
  u16*   xb     = (u16*)(base + O_XB);
  u16*   h1     = (u16*)(base + O_H1);
  u16*   h2     = (u16*)(base + O_H2);
  u16*   h3     = (u16*)(base + O_H3);
  u16*   d0     = (u16*)(base + O_D0);
  u16*   d1     = (u16*)(base + O_D1);
  float* hbuf   = (float*)(base + O_HBUF);
  int*   deg    = (int*)(base + O_DEG);
  u16*   pd0    = (u16*)(base + O_PD0);
  u16*   pd1    = (u16*)(base + O_PD1);

  hipMemsetAsync(base + O_HBUF, 0, 32768 + 262144, stream);   // hbuf + deg

  prep0<<<NN * 16 / 256, 256, 0, stream>>>(x, xb, ei, deg);
  scan1<<<256, 256, 0, stream>>>(deg, rows, bsum);
  scan2<<<1, 256, 0, stream>>>(bsum);
  scan3<<<256, 256, 0, stream>>>(rows, bsum, cursor);
  fill_kernel<<<EE / 256, 256, 0, stream>>>(ei, pos, cursor, cr);

  const float* W_e0 = (const float*)d_in[4];
  const float* R_e0 = (const float*)d_in[5];
  const float* B_e0 = (const float*)d_in[6];
  const float* W_e1 = (const float*)d_in[7];
  const float* R_e1 = (const float*)d_in[8];
  const float* B_e1 = (const float*)d_in[9];
  const float* W_e2 = (const float*)d_in[10];
  const float* R_e2 = (const float*)d_in[11];
  const float* B_e2 = (const float*)d_in[12];
  const float* W_d0 = (const float*)d_in[13];
  const float* R_d0 = (const float*)d_in[14];
  const float* B_d0 = (const float*)d_in[15];
  const float* W_d1 = (const float*)d_in[16];
  const float* R_d1 = (const float*)d_in[17];
  const float* B_d1 = (const float*)d_in[18];

  BDescs ds;
  ds.d[0]  = { W_e0, 0,      0,  16,  32, 288, 0 };
  ds.d[1]  = { W_e1, 9216,   0,  32,  64, 288, 0 };
  ds.d[2]  = { W_e2, 27648,  0,  64,  64, 288, 0 };
  ds.d[3]  = { W_e2, 46080,  32, 64,  64, 288, 0 };
  ds.d[4]  = { W_d0, 64512,  0,  128, 64, 288, 0 };
  ds.d[5]  = { W_d0, 82944,  32, 128, 64, 288, 0 };
  ds.d[6]  = { W_d0, 101376, 64, 128, 64, 288, 0 };
  ds.d[7]  = { W_d0, 119808, 96, 128, 64, 288, 0 };
  ds.d[8]  = { W_d1, 138240, 0,  96,  32, 288, 0 };
  ds.d[9]  = { W_d1, 147456, 32, 96,  32, 288, 0 };
  ds.d[10] = { W_d1, 156672, 64, 96,  32, 288, 0 };
  ds.d[11] = { R_e0, 165888, 0,  16, 32, 32, 1 };
  ds.d[12] = { R_e1, 166912, 0,  32, 64, 32, 1 };
  ds.d[13] = { R_e2, 168960, 0,  64, 64, 64, 1 };
  ds.d[14] = { R_d0, 173056, 0,  64, 64, 64, 1 };
  ds.d[15] = { R_d0, 177152, 64, 64, 64, 64, 1 };
  ds.d[16] = { R_d1, 181248, 0,  64, 32, 64, 1 };
  ds.d[17] = { R_d1, 183296, 64, 32, 32, 32, 1 };
  build_b<<<dim3(72, 18), 256, 0, stream>>>(ds, bmat);

  const int FG = NN / 8;   // 8192 blocks x 4 waves, 8 nodes/block

  // enc0: gather x (IN=16, half-wave) + root
  FArgs fe0 = { {xb, nullptr, 16, 0, 1, 0, 1, 0, 0},
                { {xb, 16, 1, 165888}, {} }, 1, B_e0, h1,
                nullptr, nullptr, 0, 0, 0 };
  fused_layer<32><<<FG, 256, 0, stream>>>(fe0, cr, rows, bmat);

  // enc1: gather h1 + root; ALSO contract agg_h1 @ W_d1[64:96] -> pd1
  FArgs fe1 = { {h1, nullptr, 32, 0, 1, 9216, 1, 0, 0},
                { {h1, 32, 1, 166912}, {} }, 1, B_e1, h2,
                nullptr, pd1, 32, 156672, 1 };
  fused_layer<64><<<FG, 256, 0, stream>>>(fe1, cr, rows, bmat);

  // enc2: gather h2 + root; ALSO contract agg_h2 @ W_d0[64:128] -> pd0
  FArgs fe2 = { {h2, nullptr, 64, 0, 0, 27648, 2, 0, 0},
                { {h2, 64, 2, 168960}, {} }, 1, B_e2, h3,
                nullptr, pd0, 64, 101376, 2 };
  fused_layer<64><<<FG, 256, 0, stream>>>(fe2, cr, rows, bmat);

  // dec0: gather h3 ONLY + pd0 partial + roots h3, h2
  FArgs fd0 = { {h3, nullptr, 64, 0, 0, 64512, 2, 0, 0},
                { {h3, 64, 2, 173056}, {h2, 64, 2, 177152} }, 2, B_d0, d0,
                pd0, nullptr, 0, 0, 0 };
  fused_layer<64><<<FG, 256, 0, stream>>>(fd0, cr, rows, bmat);

  // dec1: gather d0 ONLY + pd1 partial + roots d0, h1
  FArgs fd1 = { {d0, nullptr, 64, 0, 0, 138240, 2, 0, 0},
                { {d0, 64, 2, 181248}, {h1, 32, 1, 183296} }, 2, B_d1, d1,
                pd1, nullptr, 0, 0, 0 };
  fused_layer<32><<<FG, 256, 0, stream>>>(fd1, cr, rows, bmat);

  mlp1<<<256, 256, 0, stream>>>(d1, (const float*)d_in[19], hbuf);
  mlp2<<<1, 256, 0, stream>>>(hbuf, (const float*)d_in[20], (const float*)d_in[21],
                              (const float*)d_in[22], (float*)d_out);
}